// Round 9
// baseline (213.213 us; speedup 1.0000x reference)
//
#include <hip/hip_runtime.h>

#define E_DIM 512
#define N_DIM 512
#define B_DIM 32
#define H_DIM 8
#define D_DIM 8
#define P3    192   // 3 * H * D

typedef _Float16 half_t;
typedef __attribute__((ext_vector_type(2))) _Float16 half2v;
typedef __attribute__((ext_vector_type(4))) _Float16 half4v;
typedef __attribute__((ext_vector_type(8))) _Float16 half8v;
typedef __attribute__((ext_vector_type(4))) float f32x4;

#define PB_STRIDE 44   // halves per P-scratch row

// ---------------------------------------------------------------------------
__device__ inline float block_reduce_256(float v) {
    __shared__ float red[4];
    #pragma unroll
    for (int m = 32; m >= 1; m >>= 1) v += __shfl_xor(v, m);
    int w = threadIdx.x >> 6;
    if ((threadIdx.x & 63) == 0) red[w] = v;
    __syncthreads();
    if (threadIdx.x == 0) v = red[0] + red[1] + red[2] + red[3];
    return v;
}

__device__ inline half8v cvt8(float4 a, float4 b) {
    half8v h;
    h[0] = (half_t)a.x; h[1] = (half_t)a.y; h[2] = (half_t)a.z; h[3] = (half_t)a.w;
    h[4] = (half_t)b.x; h[5] = (half_t)b.y; h[6] = (half_t)b.z; h[7] = (half_t)b.w;
    return h;
}

// pkrtz returns __fp16 vec2; bit-cast to our _Float16 vec2
__device__ inline half2v pk2(float a, float b) {
    return __builtin_bit_cast(half2v, __builtin_amdgcn_cvt_pkrtz(a, b));
}

// ---------------------------------------------------------------------------
// K0: prep. Wth[p'][e] = f16(W[p][e]*g[e]); colsum[p'] = sum of f16-rounded w;
// b2[p'] = bias[p] + dot(W[p,:], ln_beta). Block 0 also inits y[b]=bl and
// c0acc=0 (y/ws are re-poisoned before every timed launch).
// ---------------------------------------------------------------------------
__global__ __launch_bounds__(256) void prep_w(const float* __restrict__ Wq,
                        const float* __restrict__ Wk, const float* __restrict__ Wv,
                        const float* __restrict__ gq, const float* __restrict__ gk,
                        const float* __restrict__ gv,
                        const float* __restrict__ bnq, const float* __restrict__ bnk,
                        const float* __restrict__ bnv,
                        const float* __restrict__ bq, const float* __restrict__ bk,
                        const float* __restrict__ bv,
                        const float* __restrict__ bl,
                        half_t* __restrict__ Wth, float* __restrict__ colsum,
                        float* __restrict__ b2, float* __restrict__ y,
                        float* __restrict__ c0acc) {
    int pp = blockIdx.x;     // 192
    int which = pp >> 6, p = pp & 63;
    const float* W  = (which == 0) ? Wq  : (which == 1) ? Wk  : Wv;
    const float* g  = (which == 0) ? gq  : (which == 1) ? gk  : gv;
    const float* bn = (which == 0) ? bnq : (which == 1) ? bnk : bnv;
    const float* bb = (which == 0) ? bq  : (which == 1) ? bk  : bv;
    int t = threadIdx.x;
    if (pp == 0) {
        if (t < 32) y[t] = bl[0];
        if (t == 32) c0acc[0] = 0.f;
    }
    float cs = 0.f, dt = 0.f;
    #pragma unroll
    for (int l = 0; l < 2; ++l) {
        int e = t + l * 256;
        float wv = W[p * E_DIM + e];
        half_t wh = (half_t)(wv * g[e]);
        Wth[(size_t)pp * E_DIM + e] = wh;
        cs += (float)wh;
        dt += wv * bn[e];
    }
    cs = block_reduce_256(cs);
    __syncthreads();
    dt = block_reduce_256(dt);
    if (t == 0) { colsum[pp] = cs; b2[pp] = dt + bb[p]; }
}

// ---------------------------------------------------------------------------
// K1: fused LN+QKV (blocks 0-1023, zero-LDS MFMA) AND Wl2 prep (1024-1535).
// ---------------------------------------------------------------------------
__global__ __launch_bounds__(256) void ln_qkv_wl2(const float* __restrict__ x,
                                              const half_t* __restrict__ Wth,
                                              const float* __restrict__ b2,
                                              const float* __restrict__ colsum,
                                              half_t* __restrict__ qkv16,
                                              const float* __restrict__ Wl,
                                              const float* __restrict__ Wo,
                                              const float* __restrict__ bo,
                                              float* __restrict__ Wl2,
                                              float* __restrict__ c0acc) {
    if (blockIdx.x < 1024) {
        const int t = threadIdx.x;
        const int lane = t & 63;
        const int w = t >> 6;
        const int g2 = lane >> 4, c16 = lane & 15;
        const int row0 = blockIdx.x * 16;
        const float*  xr    = x + (size_t)(row0 + c16) * E_DIM;
        const half_t* wbase = Wth + (size_t)(w * 48 + c16) * E_DIM;
        f32x4 acc[3] = {{0.f,0.f,0.f,0.f},{0.f,0.f,0.f,0.f},{0.f,0.f,0.f,0.f}};
        float sx = 0.f, sxx = 0.f;
        #pragma unroll 2
        for (int tile = 0; tile < 8; ++tile) {
            #pragma unroll
            for (int kk = 0; kk < 2; ++kk) {
                int k = tile * 64 + kk * 32 + g2 * 8;
                float4 a0 = *(const float4*)(xr + k);
                float4 a1 = *(const float4*)(xr + k + 4);
                sx  += a0.x + a0.y + a0.z + a0.w + a1.x + a1.y + a1.z + a1.w;
                sxx += a0.x*a0.x + a0.y*a0.y + a0.z*a0.z + a0.w*a0.w
                     + a1.x*a1.x + a1.y*a1.y + a1.z*a1.z + a1.w*a1.w;
                half8v af = cvt8(a0, a1);
                #pragma unroll
                for (int nt = 0; nt < 3; ++nt) {
                    half8v bf = *(const half8v*)(wbase + (size_t)nt * 16 * E_DIM + k);
                    acc[nt] = __builtin_amdgcn_mfma_f32_16x16x32_f16(af, bf, acc[nt], 0, 0, 0);
                }
            }
        }
        sx  += __shfl_xor(sx, 16);  sx  += __shfl_xor(sx, 32);
        sxx += __shfl_xor(sxx, 16); sxx += __shfl_xor(sxx, 32);
        float mean = sx * (1.f / E_DIM);
        float var  = sxx * (1.f / E_DIM) - mean * mean;
        float rs   = rsqrtf(var + 1e-5f);
        #pragma unroll
        for (int nt = 0; nt < 3; ++nt) {
            int pp = w * 48 + nt * 16 + c16;
            float cs = colsum[pp], bb = b2[pp];
            int which = pp >> 6, p = pp & 63;
            int h = p >> 3, d = p & 7;
            half_t* dst0 = qkv16 + (size_t)which * (B_DIM * H_DIM * N_DIM * D_DIM);
            #pragma unroll
            for (int r = 0; r < 4; ++r) {
                int rowi = g2 * 4 + r;
                float m_r  = __shfl(mean, rowi);
                float rs_r = __shfl(rs, rowi);
                float val = rs_r * (acc[nt][r] - m_r * cs) + bb;
                int ng = row0 + rowi;
                int b = ng >> 9, n = ng & 511;
                dst0[(((size_t)(b * H_DIM + h)) * N_DIM + n) * D_DIM + d] = (half_t)val;
            }
        }
    } else {
        __shared__ float rowS[E_DIM];
        __shared__ float partS[4][64];
        const int n = blockIdx.x - 1024;
        const int t = threadIdx.x;
        float r0 = Wl[(size_t)n * E_DIM + t];
        float r1 = Wl[(size_t)n * E_DIM + t + 256];
        rowS[t] = r0; rowS[t + 256] = r1;
        float pc = r0 * bo[t] + r1 * bo[t + 256];
        pc = block_reduce_256(pc);
        if (t == 0) atomicAdd(c0acc, pc);
        const int w = t >> 6, lane = t & 63;
        float s = 0.f;
        #pragma unroll 4
        for (int e = w * 128; e < w * 128 + 128; ++e)
            s += rowS[e] * Wo[e * 64 + lane];
        partS[w][lane] = s;
        __syncthreads();
        if (t < 64) {
            float tot = partS[0][t] + partS[1][t] + partS[2][t] + partS[3][t];
            Wl2[(t >> 3) * (N_DIM * D_DIM) + n * D_DIM + (t & 7)] = tot;
        }
    }
}

// ---------------------------------------------------------------------------
// K2: MFMA Hopfield + fused classifier. 64 rows/block (1 i-tile/wave),
// grid = 2048 -> LDS ~31.3 KB -> 5 blocks/CU resident (round 7: 4, occ 30%).
// Per wave per j32: 2 S-MFMA -> pkrtz-packed exp -> wave-private P scratch
// -> 1 U-MFMA vs KTb (col 8 = softmax denom). Iters 0-2 vs K, iter 3 vs V
// with classifier dot fused; one atomicAdd(y[b]) per block.
// ---------------------------------------------------------------------------
__global__ __launch_bounds__(256) void hopfield(const half_t* __restrict__ q16,
                                                const half_t* __restrict__ k16,
                                                const half_t* __restrict__ v16,
                                                const float* __restrict__ Wl2,
                                                const float* __restrict__ c0acc,
                                                float* __restrict__ y) {
    __shared__ half_t Kb[N_DIM * 8];            // 8 KB
    __shared__ half_t Xi[64 * 8];               // 1 KB
    __shared__ half_t KTb[16 * 536];            // 16.75 KB
    __shared__ half_t Pb[4 * 16 * PB_STRIDE];   // 5.5 KB
    const int t = threadIdx.x;
    const int lane = t & 63;
    const int w = t >> 6;
    const int g2 = lane >> 4;
    const int c16 = lane & 15;
    const int bh = blockIdx.x >> 3, seg = blockIdx.x & 7;
    const float C = 0.25f * 1.44269504088896f;
    const half_t* kg = k16 + (size_t)bh * (N_DIM * D_DIM);
    const half_t* vg = v16 + (size_t)bh * (N_DIM * D_DIM);
    const half_t* qg = q16 + (size_t)bh * (N_DIM * D_DIM) + seg * 64 * 8;
    const float* wl2p = Wl2 + (bh & 7) * (N_DIM * D_DIM) + seg * 64 * 8;

    for (int i = t; i < 16 * 536; i += 256) KTb[i] = (half_t)0.f;
    __syncthreads();
    {   // stage K rows + K^T + ones row
        int j0 = 2 * t;
        half8v r0 = *(const half8v*)(kg + j0 * 8);
        half8v r1 = *(const half8v*)(kg + j0 * 8 + 8);
        *(half8v*)&Kb[j0 * 8] = r0;
        *(half8v*)&Kb[j0 * 8 + 8] = r1;
        #pragma unroll
        for (int d = 0; d < 8; ++d) {
            KTb[d * 536 + j0] = r0[d];
            KTb[d * 536 + j0 + 1] = r1[d];
        }
        KTb[8 * 536 + j0] = (half_t)1.f;
        KTb[8 * 536 + j0 + 1] = (half_t)1.f;
    }
    if (t < 64) {   // stage Xi = C * q (64 block-local rows)
        half8v hq = *(const half8v*)(qg + t * 8);
        half8v h;
        #pragma unroll
        for (int d = 0; d < 8; ++d) h[d] = (half_t)(C * (float)hq[d]);
        *(half8v*)&Xi[t * 8] = h;
    }
    __syncthreads();

    const half_t* zsrc = &KTb[9 * 536];   // 16B-aligned zeros
    half_t* myP = &Pb[w * 16 * PB_STRIDE];
    float fsum = 0.f;

    for (int it = 0; it < 4; ++it) {
        if (it == 3) {   // swap KTb rows 0-7 to V^T
            __syncthreads();
            int j0 = 2 * t;
            half8v r0 = *(const half8v*)(vg + j0 * 8);
            half8v r1 = *(const half8v*)(vg + j0 * 8 + 8);
            #pragma unroll
            for (int d = 0; d < 8; ++d) {
                KTb[d * 536 + j0] = r0[d];
                KTb[d * 536 + j0 + 1] = r1[d];
            }
            __syncthreads();
        }
        const half_t* xp = (g2 == 0) ? &Xi[(w * 16 + c16) * 8] : zsrc;
        half8v bxi = *(const half8v*)xp;
        f32x4 U = {0.f, 0.f, 0.f, 0.f};
        for (int j32 = 0; j32 < 16; ++j32) {
            #pragma unroll
            for (int hh = 0; hh < 2; ++hh) {
                int jt16 = j32 * 2 + hh;
                const half_t* akp = (g2 == 0) ? &Kb[(jt16 * 16 + c16) * 8] : zsrc;
                half8v ak = *(const half8v*)akp;
                f32x4 S = {0.f, 0.f, 0.f, 0.f};
                S = __builtin_amdgcn_mfma_f32_16x16x32_f16(ak, bxi, S, 0, 0, 0);
                half2v lo = pk2(__builtin_amdgcn_exp2f(S[0]), __builtin_amdgcn_exp2f(S[1]));
                half2v hi = pk2(__builtin_amdgcn_exp2f(S[2]), __builtin_amdgcn_exp2f(S[3]));
                half4v p = __builtin_shufflevector(lo, hi, 0, 1, 2, 3);
                *(half4v*)&myP[c16 * PB_STRIDE + hh * 16 + g2 * 4] = p;
            }
            half4v alo = *(const half4v*)&myP[c16 * PB_STRIDE + g2 * 8];
            half4v ahi = *(const half4v*)&myP[c16 * PB_STRIDE + g2 * 8 + 4];
            half8v ap = __builtin_shufflevector(alo, ahi, 0, 1, 2, 3, 4, 5, 6, 7);
            half8v bKT = *(const half8v*)&KTb[c16 * 536 + j32 * 32 + g2 * 8];
            U = __builtin_amdgcn_mfma_f32_16x16x32_f16(ap, bKT, U, 0, 0, 0);
        }
        int srcl = (lane & 48) | 8;   // lane holding col 8 (= denom) of my rows
        #pragma unroll
        for (int r = 0; r < 4; ++r) {
            float l0 = __shfl(U[r], srcl, 64);
            float invl = __builtin_amdgcn_rcpf(l0);
            if (c16 < 8) {
                int i0 = w * 16 + g2 * 4 + r;
                if (it < 3) {
                    Xi[i0 * 8 + c16] = (half_t)(U[r] * (C * invl));
                } else {
                    fsum += (U[r] * invl) * wl2p[i0 * 8 + c16];
                }
            }
        }
    }
    float tot = block_reduce_256(fsum);
    if (t == 0) atomicAdd(&y[bh >> 3], tot);
    if (blockIdx.x == 0 && t < 32) {
        atomicAdd(&y[t], c0acc[0]);
    }
}

// ---------------------------------------------------------------------------
extern "C" void kernel_launch(void* const* d_in, const int* in_sizes, int n_in,
                              void* d_out, int out_size, void* d_ws, size_t ws_size,
                              hipStream_t stream) {
    const float* x   = (const float*)d_in[0];
    const float* g_q = (const float*)d_in[1];
    const float* b_q = (const float*)d_in[2];
    const float* g_k = (const float*)d_in[3];
    const float* b_k = (const float*)d_in[4];
    const float* g_v = (const float*)d_in[5];
    const float* b_v = (const float*)d_in[6];
    const float* Wq  = (const float*)d_in[7];
    const float* bq  = (const float*)d_in[8];
    const float* Wk  = (const float*)d_in[9];
    const float* bk  = (const float*)d_in[10];
    const float* Wv  = (const float*)d_in[11];
    const float* bv  = (const float*)d_in[12];
    const float* Wo  = (const float*)d_in[13];
    const float* bo  = (const float*)d_in[14];
    const float* Wl  = (const float*)d_in[15];
    const float* bl  = (const float*)d_in[16];
    float* out = (float*)d_out;

    float* ws = (float*)d_ws;
    float*  colsum = ws;                      // 192
    float*  b2     = ws + 192;                // 192
    float*  c0acc  = ws + 384;                // 1 (+pad to 64)
    float*  Wl2    = ws + 448;                // 32768
    half_t* Wth    = (half_t*)(ws + 33216);   // 98304 halves = 49152 floats
    half_t* qkv16  = (half_t*)(ws + 82368);   // 3*1048576 halves

    half_t* q16 = qkv16;
    half_t* k16 = qkv16 + 1048576;
    half_t* v16 = qkv16 + 2097152;

    prep_w    <<<192, 256, 0, stream>>>(Wq, Wk, Wv, g_q, g_k, g_v,
                                        b_q, b_k, b_v, bq, bk, bv, bl,
                                        Wth, colsum, b2, out, c0acc);
    ln_qkv_wl2<<<1536, 256, 0, stream>>>(x, Wth, b2, colsum, qkv16,
                                         Wl, Wo, bo, Wl2, c0acc);
    hopfield  <<<2048, 256, 0, stream>>>(q16, k16, v16, Wl2, c0acc, out);
}

// Round 10
// 193.926 us; speedup vs baseline: 1.0995x; 1.0995x over previous
//
#include <hip/hip_runtime.h>

#define E_DIM 512
#define N_DIM 512
#define B_DIM 32
#define H_DIM 8
#define D_DIM 8
#define P3    192   // 3 * H * D

typedef _Float16 half_t;
typedef __attribute__((ext_vector_type(4))) _Float16 half4v;
typedef __attribute__((ext_vector_type(8))) _Float16 half8v;
typedef __attribute__((ext_vector_type(4))) float f32x4;

#define PB_STRIDE 44   // halves per P-scratch row

// ---------------------------------------------------------------------------
__device__ inline float block_reduce_256(float v) {
    __shared__ float red[4];
    #pragma unroll
    for (int m = 32; m >= 1; m >>= 1) v += __shfl_xor(v, m);
    int w = threadIdx.x >> 6;
    if ((threadIdx.x & 63) == 0) red[w] = v;
    __syncthreads();
    if (threadIdx.x == 0) v = red[0] + red[1] + red[2] + red[3];
    return v;
}

__device__ inline half8v cvt8(float4 a, float4 b) {
    half8v h;
    h[0] = (half_t)a.x; h[1] = (half_t)a.y; h[2] = (half_t)a.z; h[3] = (half_t)a.w;
    h[4] = (half_t)b.x; h[5] = (half_t)b.y; h[6] = (half_t)b.z; h[7] = (half_t)b.w;
    return h;
}

// ---------------------------------------------------------------------------
// K0: prep. Wth[p'][e] = f16(W[p][e]*g[e]); colsum[p'] = sum of f16-rounded w;
// b2[p'] = bias[p] + dot(W[p,:], ln_beta). Block 0 also inits y[b]=bl and
// c0acc=0 (y/ws are re-poisoned before every timed launch).
// ---------------------------------------------------------------------------
__global__ __launch_bounds__(256) void prep_w(const float* __restrict__ Wq,
                        const float* __restrict__ Wk, const float* __restrict__ Wv,
                        const float* __restrict__ gq, const float* __restrict__ gk,
                        const float* __restrict__ gv,
                        const float* __restrict__ bnq, const float* __restrict__ bnk,
                        const float* __restrict__ bnv,
                        const float* __restrict__ bq, const float* __restrict__ bk,
                        const float* __restrict__ bv,
                        const float* __restrict__ bl,
                        half_t* __restrict__ Wth, float* __restrict__ colsum,
                        float* __restrict__ b2, float* __restrict__ y,
                        float* __restrict__ c0acc) {
    int pp = blockIdx.x;     // 192
    int which = pp >> 6, p = pp & 63;
    const float* W  = (which == 0) ? Wq  : (which == 1) ? Wk  : Wv;
    const float* g  = (which == 0) ? gq  : (which == 1) ? gk  : gv;
    const float* bn = (which == 0) ? bnq : (which == 1) ? bnk : bnv;
    const float* bb = (which == 0) ? bq  : (which == 1) ? bk  : bv;
    int t = threadIdx.x;
    if (pp == 0) {
        if (t < 32) y[t] = bl[0];
        if (t == 32) c0acc[0] = 0.f;
    }
    float cs = 0.f, dt = 0.f;
    #pragma unroll
    for (int l = 0; l < 2; ++l) {
        int e = t + l * 256;
        float wv = W[p * E_DIM + e];
        half_t wh = (half_t)(wv * g[e]);
        Wth[(size_t)pp * E_DIM + e] = wh;
        cs += (float)wh;
        dt += wv * bn[e];
    }
    cs = block_reduce_256(cs);
    __syncthreads();
    dt = block_reduce_256(dt);
    if (t == 0) { colsum[pp] = cs; b2[pp] = dt + bb[p]; }
}

// ---------------------------------------------------------------------------
// K1: blocks 0-1023: fused LN+QKV (zero-LDS MFMA, verbatim round 7).
// Blocks 1024-1055: Wl2 via MFMA: 32 blocks x 4 waves; block = 16 n-rows,
// wave = 16 p-cols, K=512 (16 MFMA/wave). Replaces the 512-block
// serial-chain version (128 L2-latency-bound loads/thread). Wave 0 also
// accumulates pc = dot(Wl[n,:], bo) in f32 -> one atomicAdd(c0acc)/block.
// ---------------------------------------------------------------------------
__global__ __launch_bounds__(256) void ln_qkv_wl2(const float* __restrict__ x,
                                              const half_t* __restrict__ Wth,
                                              const float* __restrict__ b2,
                                              const float* __restrict__ colsum,
                                              half_t* __restrict__ qkv16,
                                              const float* __restrict__ Wl,
                                              const float* __restrict__ Wo,
                                              const float* __restrict__ bo,
                                              float* __restrict__ Wl2,
                                              float* __restrict__ c0acc) {
    if (blockIdx.x < 1024) {
        const int t = threadIdx.x;
        const int lane = t & 63;
        const int w = t >> 6;
        const int g2 = lane >> 4, c16 = lane & 15;
        const int row0 = blockIdx.x * 16;
        const float*  xr    = x + (size_t)(row0 + c16) * E_DIM;
        const half_t* wbase = Wth + (size_t)(w * 48 + c16) * E_DIM;
        f32x4 acc[3] = {{0.f,0.f,0.f,0.f},{0.f,0.f,0.f,0.f},{0.f,0.f,0.f,0.f}};
        float sx = 0.f, sxx = 0.f;
        #pragma unroll 2
        for (int tile = 0; tile < 8; ++tile) {
            #pragma unroll
            for (int kk = 0; kk < 2; ++kk) {
                int k = tile * 64 + kk * 32 + g2 * 8;
                float4 a0 = *(const float4*)(xr + k);
                float4 a1 = *(const float4*)(xr + k + 4);
                sx  += a0.x + a0.y + a0.z + a0.w + a1.x + a1.y + a1.z + a1.w;
                sxx += a0.x*a0.x + a0.y*a0.y + a0.z*a0.z + a0.w*a0.w
                     + a1.x*a1.x + a1.y*a1.y + a1.z*a1.z + a1.w*a1.w;
                half8v af = cvt8(a0, a1);
                #pragma unroll
                for (int nt = 0; nt < 3; ++nt) {
                    half8v bf = *(const half8v*)(wbase + (size_t)nt * 16 * E_DIM + k);
                    acc[nt] = __builtin_amdgcn_mfma_f32_16x16x32_f16(af, bf, acc[nt], 0, 0, 0);
                }
            }
        }
        sx  += __shfl_xor(sx, 16);  sx  += __shfl_xor(sx, 32);
        sxx += __shfl_xor(sxx, 16); sxx += __shfl_xor(sxx, 32);
        float mean = sx * (1.f / E_DIM);
        float var  = sxx * (1.f / E_DIM) - mean * mean;
        float rs   = rsqrtf(var + 1e-5f);
        #pragma unroll
        for (int nt = 0; nt < 3; ++nt) {
            int pp = w * 48 + nt * 16 + c16;
            float cs = colsum[pp], bb = b2[pp];
            int which = pp >> 6, p = pp & 63;
            int h = p >> 3, d = p & 7;
            half_t* dst0 = qkv16 + (size_t)which * (B_DIM * H_DIM * N_DIM * D_DIM);
            #pragma unroll
            for (int r = 0; r < 4; ++r) {
                int rowi = g2 * 4 + r;
                float m_r  = __shfl(mean, rowi);
                float rs_r = __shfl(rs, rowi);
                float val = rs_r * (acc[nt][r] - m_r * cs) + bb;
                int ng = row0 + rowi;
                int b = ng >> 9, n = ng & 511;
                dst0[(((size_t)(b * H_DIM + h)) * N_DIM + n) * D_DIM + d] = (half_t)val;
            }
        }
    } else {
        // ---- Wl2 MFMA: blk in [0,32) ----
        const int blk = blockIdx.x - 1024;
        const int t = threadIdx.x;
        const int lane = t & 63;
        const int w = t >> 6;
        const int g2 = lane >> 4, c16 = lane & 15;
        const int n0 = blk * 16;
        const int pcol = w * 16;
        f32x4 acc = {0.f, 0.f, 0.f, 0.f};
        float pc = 0.f;
        const float* arow = Wl + (size_t)(n0 + c16) * E_DIM;
        #pragma unroll 2
        for (int k0 = 0; k0 < E_DIM; k0 += 32) {
            int kbase = k0 + g2 * 8;
            float4 a0 = *(const float4*)(arow + kbase);
            float4 a1 = *(const float4*)(arow + kbase + 4);
            if (w == 0) {
                float4 b0 = *(const float4*)(bo + kbase);
                float4 b1 = *(const float4*)(bo + kbase + 4);
                pc += a0.x*b0.x + a0.y*b0.y + a0.z*b0.z + a0.w*b0.w
                    + a1.x*b1.x + a1.y*b1.y + a1.z*b1.z + a1.w*b1.w;
            }
            half8v af = cvt8(a0, a1);
            half8v bf;
            #pragma unroll
            for (int j = 0; j < 8; ++j)
                bf[j] = (half_t)Wo[(size_t)(kbase + j) * 64 + pcol + c16];
            acc = __builtin_amdgcn_mfma_f32_16x16x32_f16(af, bf, acc, 0, 0, 0);
        }
        int p = pcol + c16, h = p >> 3, d = p & 7;
        #pragma unroll
        for (int r = 0; r < 4; ++r) {
            int n = n0 + g2 * 4 + r;
            Wl2[h * (N_DIM * D_DIM) + n * D_DIM + d] = acc[r];
        }
        if (w == 0) {
            pc += __shfl_xor(pc, 16); pc += __shfl_xor(pc, 32);
            pc += __shfl_xor(pc, 1);  pc += __shfl_xor(pc, 2);
            pc += __shfl_xor(pc, 4);  pc += __shfl_xor(pc, 8);
            if (lane == 0) atomicAdd(c0acc, pc);
        }
    }
}

// ---------------------------------------------------------------------------
// K2: MFMA Hopfield + fused classifier — VERBATIM round-7 body (53.9 us,
// VGPR 60). Round 9's 64-row restructure blew VGPR to 128 (occupancy 19%)
// and doubled staging; reverted. 128 rows/block, grid 1024.
// ---------------------------------------------------------------------------
__global__ __launch_bounds__(256) void hopfield(const half_t* __restrict__ q16,
                                                const half_t* __restrict__ k16,
                                                const half_t* __restrict__ v16,
                                                const float* __restrict__ Wl2,
                                                const float* __restrict__ c0acc,
                                                float* __restrict__ y) {
    __shared__ half_t Kb[N_DIM * 8];
    __shared__ half_t Xi[128 * 8];
    __shared__ half_t KTb[16 * 536];
    __shared__ half_t Pb[4 * 32 * PB_STRIDE];
    const int t = threadIdx.x;
    const int lane = t & 63;
    const int w = t >> 6;
    const int g2 = lane >> 4;
    const int c16 = lane & 15;
    const int bh = blockIdx.x >> 2, seg = blockIdx.x & 3;
    const float C = 0.25f * 1.44269504088896f;
    const half_t* kg = k16 + (size_t)bh * (N_DIM * D_DIM);
    const half_t* vg = v16 + (size_t)bh * (N_DIM * D_DIM);
    const half_t* qg = q16 + (size_t)bh * (N_DIM * D_DIM) + seg * 128 * 8;
    const float* wl2p = Wl2 + (bh & 7) * (N_DIM * D_DIM) + seg * 128 * 8;

    for (int i = t; i < 16 * 536; i += 256) KTb[i] = (half_t)0.f;
    __syncthreads();
    {   // stage K rows + K^T + ones row
        int j0 = 2 * t;
        half8v r0 = *(const half8v*)(kg + j0 * 8);
        half8v r1 = *(const half8v*)(kg + j0 * 8 + 8);
        *(half8v*)&Kb[j0 * 8] = r0;
        *(half8v*)&Kb[j0 * 8 + 8] = r1;
        #pragma unroll
        for (int d = 0; d < 8; ++d) {
            KTb[d * 536 + j0] = r0[d];
            KTb[d * 536 + j0 + 1] = r1[d];
        }
        KTb[8 * 536 + j0] = (half_t)1.f;
        KTb[8 * 536 + j0 + 1] = (half_t)1.f;
    }
    if (t < 128) {   // stage Xi = C * q
        half8v hq = *(const half8v*)(qg + t * 8);
        half8v h;
        #pragma unroll
        for (int d = 0; d < 8; ++d) h[d] = (half_t)(C * (float)hq[d]);
        *(half8v*)&Xi[t * 8] = h;
    }
    __syncthreads();

    const half_t* zsrc = &KTb[9 * 536];   // 16B-aligned zeros
    half_t* myP = &Pb[w * 32 * PB_STRIDE];
    float fsum = 0.f;

    for (int it = 0; it < 4; ++it) {
        if (it == 3) {   // swap KTb rows 0-7 to V^T
            __syncthreads();
            int j0 = 2 * t;
            half8v r0 = *(const half8v*)(vg + j0 * 8);
            half8v r1 = *(const half8v*)(vg + j0 * 8 + 8);
            #pragma unroll
            for (int d = 0; d < 8; ++d) {
                KTb[d * 536 + j0] = r0[d];
                KTb[d * 536 + j0 + 1] = r1[d];
            }
            __syncthreads();
        }
        const half_t* x0p = (g2 == 0) ? &Xi[(w * 32 + c16) * 8] : zsrc;
        const half_t* x1p = (g2 == 0) ? &Xi[(w * 32 + 16 + c16) * 8] : zsrc;
        half8v bxi0 = *(const half8v*)x0p;
        half8v bxi1 = *(const half8v*)x1p;
        f32x4 U0 = {0.f, 0.f, 0.f, 0.f}, U1 = {0.f, 0.f, 0.f, 0.f};
        for (int j32 = 0; j32 < 16; ++j32) {
            #pragma unroll
            for (int hh = 0; hh < 2; ++hh) {
                int jt16 = j32 * 2 + hh;
                const half_t* akp = (g2 == 0) ? &Kb[(jt16 * 16 + c16) * 8] : zsrc;
                half8v ak = *(const half8v*)akp;
                f32x4 S0 = {0.f, 0.f, 0.f, 0.f}, S1 = {0.f, 0.f, 0.f, 0.f};
                S0 = __builtin_amdgcn_mfma_f32_16x16x32_f16(ak, bxi0, S0, 0, 0, 0);
                S1 = __builtin_amdgcn_mfma_f32_16x16x32_f16(ak, bxi1, S1, 0, 0, 0);
                half4v p0, p1;
                #pragma unroll
                for (int r = 0; r < 4; ++r) {
                    p0[r] = (half_t)__builtin_amdgcn_exp2f(S0[r]);
                    p1[r] = (half_t)__builtin_amdgcn_exp2f(S1[r]);
                }
                int joff = hh * 16 + g2 * 4;
                *(half4v*)&myP[c16 * PB_STRIDE + joff] = p0;
                *(half4v*)&myP[(16 + c16) * PB_STRIDE + joff] = p1;
            }
            half4v alo0 = *(const half4v*)&myP[c16 * PB_STRIDE + g2 * 8];
            half4v ahi0 = *(const half4v*)&myP[c16 * PB_STRIDE + g2 * 8 + 4];
            half4v alo1 = *(const half4v*)&myP[(16 + c16) * PB_STRIDE + g2 * 8];
            half4v ahi1 = *(const half4v*)&myP[(16 + c16) * PB_STRIDE + g2 * 8 + 4];
            half8v ap0 = __builtin_shufflevector(alo0, ahi0, 0, 1, 2, 3, 4, 5, 6, 7);
            half8v ap1 = __builtin_shufflevector(alo1, ahi1, 0, 1, 2, 3, 4, 5, 6, 7);
            half8v b2f = *(const half8v*)&KTb[c16 * 536 + j32 * 32 + g2 * 8];
            U0 = __builtin_amdgcn_mfma_f32_16x16x32_f16(ap0, b2f, U0, 0, 0, 0);
            U1 = __builtin_amdgcn_mfma_f32_16x16x32_f16(ap1, b2f, U1, 0, 0, 0);
        }
        int srcl = (lane & 48) | 8;
        #pragma unroll
        for (int r = 0; r < 4; ++r) {
            float l0 = __shfl(U0[r], srcl, 64);
            float l1 = __shfl(U1[r], srcl, 64);
            if (c16 < 8) {
                int i0 = w * 32 + g2 * 4 + r;
                int i1 = i0 + 16;
                if (it < 3) {
                    Xi[i0 * 8 + c16] = (half_t)(U0[r] * (C / l0));
                    Xi[i1 * 8 + c16] = (half_t)(U1[r] * (C / l1));
                } else {
                    fsum += (U0[r] / l0) * wl2p[i0 * 8 + c16]
                          + (U1[r] / l1) * wl2p[i1 * 8 + c16];
                }
            }
        }
    }
    float tot = block_reduce_256(fsum);
    if (t == 0) atomicAdd(&y[bh >> 3], tot);
    if (blockIdx.x == 0 && t < 32) {
        atomicAdd(&y[t], c0acc[0]);
    }
}

// ---------------------------------------------------------------------------
extern "C" void kernel_launch(void* const* d_in, const int* in_sizes, int n_in,
                              void* d_out, int out_size, void* d_ws, size_t ws_size,
                              hipStream_t stream) {
    const float* x   = (const float*)d_in[0];
    const float* g_q = (const float*)d_in[1];
    const float* b_q = (const float*)d_in[2];
    const float* g_k = (const float*)d_in[3];
    const float* b_k = (const float*)d_in[4];
    const float* g_v = (const float*)d_in[5];
    const float* b_v = (const float*)d_in[6];
    const float* Wq  = (const float*)d_in[7];
    const float* bq  = (const float*)d_in[8];
    const float* Wk  = (const float*)d_in[9];
    const float* bk  = (const float*)d_in[10];
    const float* Wv  = (const float*)d_in[11];
    const float* bv  = (const float*)d_in[12];
    const float* Wo  = (const float*)d_in[13];
    const float* bo  = (const float*)d_in[14];
    const float* Wl  = (const float*)d_in[15];
    const float* bl  = (const float*)d_in[16];
    float* out = (float*)d_out;

    float* ws = (float*)d_ws;
    float*  colsum = ws;                      // 192
    float*  b2     = ws + 192;                // 192
    float*  c0acc  = ws + 384;                // 1 (+pad to 64)
    float*  Wl2    = ws + 448;                // 32768
    half_t* Wth    = (half_t*)(ws + 33216);   // 98304 halves = 49152 floats
    half_t* qkv16  = (half_t*)(ws + 82368);   // 3*1048576 halves

    half_t* q16 = qkv16;
    half_t* k16 = qkv16 + 1048576;
    half_t* v16 = qkv16 + 2097152;

    prep_w    <<<192, 256, 0, stream>>>(Wq, Wk, Wv, g_q, g_k, g_v,
                                        b_q, b_k, b_v, bq, bk, bv, bl,
                                        Wth, colsum, b2, out, c0acc);
    ln_qkv_wl2<<<1056, 256, 0, stream>>>(x, Wth, b2, colsum, qkv16,
                                         Wl, Wo, bo, Wl2, c0acc);
    hopfield  <<<1024, 256, 0, stream>>>(q16, k16, v16, Wl2, c0acc, out);
}

// Round 11
// 190.401 us; speedup vs baseline: 1.1198x; 1.0185x over previous
//
#include <hip/hip_runtime.h>

#define E_DIM 512
#define N_DIM 512
#define B_DIM 32
#define H_DIM 8
#define D_DIM 8
#define P3    192   // 3 * H * D

typedef _Float16 half_t;
typedef __attribute__((ext_vector_type(2))) _Float16 half2v;
typedef __attribute__((ext_vector_type(4))) _Float16 half4v;
typedef __attribute__((ext_vector_type(8))) _Float16 half8v;
typedef __attribute__((ext_vector_type(4))) float f32x4;

#define PB_STRIDE 36   // halves per P-scratch row (stride is conflict-neutral: r7)

// ---------------------------------------------------------------------------
__device__ inline float block_reduce_256(float v) {
    __shared__ float red[4];
    #pragma unroll
    for (int m = 32; m >= 1; m >>= 1) v += __shfl_xor(v, m);
    int w = threadIdx.x >> 6;
    if ((threadIdx.x & 63) == 0) red[w] = v;
    __syncthreads();
    if (threadIdx.x == 0) v = red[0] + red[1] + red[2] + red[3];
    return v;
}

__device__ inline half8v cvt8(float4 a, float4 b) {
    half8v h;
    h[0] = (half_t)a.x; h[1] = (half_t)a.y; h[2] = (half_t)a.z; h[3] = (half_t)a.w;
    h[4] = (half_t)b.x; h[5] = (half_t)b.y; h[6] = (half_t)b.z; h[7] = (half_t)b.w;
    return h;
}

// v_cvt_pkrtz returns __fp16 vec2; bit-cast to our _Float16 vec2 (round-8 fix)
__device__ inline half2v pk2(float a, float b) {
    return __builtin_bit_cast(half2v, __builtin_amdgcn_cvt_pkrtz(a, b));
}

// ---------------------------------------------------------------------------
// K0: prep. Wth[p'][e] = f16(W[p][e]*g[e]); colsum[p'] = sum of f16-rounded w;
// b2[p'] = bias[p] + dot(W[p,:], ln_beta). Block 0 also inits y[b]=bl and
// c0acc=0 (y/ws are re-poisoned before every timed launch).
// ---------------------------------------------------------------------------
__global__ __launch_bounds__(256) void prep_w(const float* __restrict__ Wq,
                        const float* __restrict__ Wk, const float* __restrict__ Wv,
                        const float* __restrict__ gq, const float* __restrict__ gk,
                        const float* __restrict__ gv,
                        const float* __restrict__ bnq, const float* __restrict__ bnk,
                        const float* __restrict__ bnv,
                        const float* __restrict__ bq, const float* __restrict__ bk,
                        const float* __restrict__ bv,
                        const float* __restrict__ bl,
                        half_t* __restrict__ Wth, float* __restrict__ colsum,
                        float* __restrict__ b2, float* __restrict__ y,
                        float* __restrict__ c0acc) {
    int pp = blockIdx.x;     // 192
    int which = pp >> 6, p = pp & 63;
    const float* W  = (which == 0) ? Wq  : (which == 1) ? Wk  : Wv;
    const float* g  = (which == 0) ? gq  : (which == 1) ? gk  : gv;
    const float* bn = (which == 0) ? bnq : (which == 1) ? bnk : bnv;
    const float* bb = (which == 0) ? bq  : (which == 1) ? bk  : bv;
    int t = threadIdx.x;
    if (pp == 0) {
        if (t < 32) y[t] = bl[0];
        if (t == 32) c0acc[0] = 0.f;
    }
    float cs = 0.f, dt = 0.f;
    #pragma unroll
    for (int l = 0; l < 2; ++l) {
        int e = t + l * 256;
        float wv = W[p * E_DIM + e];
        half_t wh = (half_t)(wv * g[e]);
        Wth[(size_t)pp * E_DIM + e] = wh;
        cs += (float)wh;
        dt += wv * bn[e];
    }
    cs = block_reduce_256(cs);
    __syncthreads();
    dt = block_reduce_256(dt);
    if (t == 0) { colsum[pp] = cs; b2[pp] = dt + bb[p]; }
}

// ---------------------------------------------------------------------------
// K1: blocks 0-1023: fused LN+QKV (zero-LDS MFMA). Blocks 1024-1055: Wl2 via
// MFMA (runs concurrently with / hidden under the ln blocks — r10 evidence).
// ---------------------------------------------------------------------------
__global__ __launch_bounds__(256) void ln_qkv_wl2(const float* __restrict__ x,
                                              const half_t* __restrict__ Wth,
                                              const float* __restrict__ b2,
                                              const float* __restrict__ colsum,
                                              half_t* __restrict__ qkv16,
                                              const float* __restrict__ Wl,
                                              const float* __restrict__ Wo,
                                              const float* __restrict__ bo,
                                              float* __restrict__ Wl2,
                                              float* __restrict__ c0acc) {
    if (blockIdx.x < 1024) {
        const int t = threadIdx.x;
        const int lane = t & 63;
        const int w = t >> 6;
        const int g2 = lane >> 4, c16 = lane & 15;
        const int row0 = blockIdx.x * 16;
        const float*  xr    = x + (size_t)(row0 + c16) * E_DIM;
        const half_t* wbase = Wth + (size_t)(w * 48 + c16) * E_DIM;
        f32x4 acc[3] = {{0.f,0.f,0.f,0.f},{0.f,0.f,0.f,0.f},{0.f,0.f,0.f,0.f}};
        float sx = 0.f, sxx = 0.f;
        #pragma unroll 2
        for (int tile = 0; tile < 8; ++tile) {
            #pragma unroll
            for (int kk = 0; kk < 2; ++kk) {
                int k = tile * 64 + kk * 32 + g2 * 8;
                float4 a0 = *(const float4*)(xr + k);
                float4 a1 = *(const float4*)(xr + k + 4);
                sx  += a0.x + a0.y + a0.z + a0.w + a1.x + a1.y + a1.z + a1.w;
                sxx += a0.x*a0.x + a0.y*a0.y + a0.z*a0.z + a0.w*a0.w
                     + a1.x*a1.x + a1.y*a1.y + a1.z*a1.z + a1.w*a1.w;
                half8v af = cvt8(a0, a1);
                #pragma unroll
                for (int nt = 0; nt < 3; ++nt) {
                    half8v bf = *(const half8v*)(wbase + (size_t)nt * 16 * E_DIM + k);
                    acc[nt] = __builtin_amdgcn_mfma_f32_16x16x32_f16(af, bf, acc[nt], 0, 0, 0);
                }
            }
        }
        sx  += __shfl_xor(sx, 16);  sx  += __shfl_xor(sx, 32);
        sxx += __shfl_xor(sxx, 16); sxx += __shfl_xor(sxx, 32);
        float mean = sx * (1.f / E_DIM);
        float var  = sxx * (1.f / E_DIM) - mean * mean;
        float rs   = rsqrtf(var + 1e-5f);
        #pragma unroll
        for (int nt = 0; nt < 3; ++nt) {
            int pp = w * 48 + nt * 16 + c16;
            float cs = colsum[pp], bb = b2[pp];
            int which = pp >> 6, p = pp & 63;
            int h = p >> 3, d = p & 7;
            half_t* dst0 = qkv16 + (size_t)which * (B_DIM * H_DIM * N_DIM * D_DIM);
            #pragma unroll
            for (int r = 0; r < 4; ++r) {
                int rowi = g2 * 4 + r;
                float m_r  = __shfl(mean, rowi);
                float rs_r = __shfl(rs, rowi);
                float val = rs_r * (acc[nt][r] - m_r * cs) + bb;
                int ng = row0 + rowi;
                int b = ng >> 9, n = ng & 511;
                dst0[(((size_t)(b * H_DIM + h)) * N_DIM + n) * D_DIM + d] = (half_t)val;
            }
        }
    } else {
        // ---- Wl2 MFMA: blk in [0,32) ----
        const int blk = blockIdx.x - 1024;
        const int t = threadIdx.x;
        const int lane = t & 63;
        const int w = t >> 6;
        const int g2 = lane >> 4, c16 = lane & 15;
        const int n0 = blk * 16;
        const int pcol = w * 16;
        f32x4 acc = {0.f, 0.f, 0.f, 0.f};
        float pc = 0.f;
        const float* arow = Wl + (size_t)(n0 + c16) * E_DIM;
        #pragma unroll 2
        for (int k0 = 0; k0 < E_DIM; k0 += 32) {
            int kbase = k0 + g2 * 8;
            float4 a0 = *(const float4*)(arow + kbase);
            float4 a1 = *(const float4*)(arow + kbase + 4);
            if (w == 0) {
                float4 b0 = *(const float4*)(bo + kbase);
                float4 b1 = *(const float4*)(bo + kbase + 4);
                pc += a0.x*b0.x + a0.y*b0.y + a0.z*b0.z + a0.w*b0.w
                    + a1.x*b1.x + a1.y*b1.y + a1.z*b1.z + a1.w*b1.w;
            }
            half8v af = cvt8(a0, a1);
            half8v bf;
            #pragma unroll
            for (int j = 0; j < 8; ++j)
                bf[j] = (half_t)Wo[(size_t)(kbase + j) * 64 + pcol + c16];
            acc = __builtin_amdgcn_mfma_f32_16x16x32_f16(af, bf, acc, 0, 0, 0);
        }
        int p = pcol + c16, h = p >> 3, d = p & 7;
        #pragma unroll
        for (int r = 0; r < 4; ++r) {
            int n = n0 + g2 * 4 + r;
            Wl2[h * (N_DIM * D_DIM) + n * D_DIM + d] = acc[r];
        }
        if (w == 0) {
            pc += __shfl_xor(pc, 16); pc += __shfl_xor(pc, 32);
            pc += __shfl_xor(pc, 1);  pc += __shfl_xor(pc, 2);
            pc += __shfl_xor(pc, 4);  pc += __shfl_xor(pc, 8);
            if (lane == 0) atomicAdd(c0acc, pc);
        }
    }
}

// ---------------------------------------------------------------------------
// K2: MFMA Hopfield + fused classifier. r7 body (128 rows/block, grid 1024,
// VGPR 60) with three targeted changes:
//  (1) Pb per-i-tile (16 rows, write->consume per tile; same-wave in-order
//      LDS ops make the reuse safe) + stride 36 + KTb zero-init row 9 only
//      -> LDS 38.9 KB -> 31.3 KB -> 5 blocks/CU (was 4).
//  (2) v_cvt_pkrtz packing for P (halves cvt issue count).
//  (3) rcpf replaces the 32 IEEE divides per lane.
// KTb rows 10-15 left garbage: only ever read as B-cols 9-15 of U, whose
// outputs are never consumed (matmul keeps garbage column-isolated).
// ---------------------------------------------------------------------------
__global__ __launch_bounds__(256) void hopfield(const half_t* __restrict__ q16,
                                                const half_t* __restrict__ k16,
                                                const half_t* __restrict__ v16,
                                                const float* __restrict__ Wl2,
                                                const float* __restrict__ c0acc,
                                                float* __restrict__ y) {
    __shared__ half_t Kb[N_DIM * 8];            // 8 KB
    __shared__ half_t Xi[128 * 8];              // 2 KB
    __shared__ half_t KTb[16 * 536];            // 16.75 KB
    __shared__ half_t Pb[4 * 16 * PB_STRIDE];   // 4.5 KB
    const int t = threadIdx.x;
    const int lane = t & 63;
    const int w = t >> 6;
    const int g2 = lane >> 4;
    const int c16 = lane & 15;
    const int bh = blockIdx.x >> 2, seg = blockIdx.x & 3;
    const float C = 0.25f * 1.44269504088896f;
    const half_t* kg = k16 + (size_t)bh * (N_DIM * D_DIM);
    const half_t* vg = v16 + (size_t)bh * (N_DIM * D_DIM);
    const half_t* qg = q16 + (size_t)bh * (N_DIM * D_DIM) + seg * 128 * 8;
    const float* wl2p = Wl2 + (bh & 7) * (N_DIM * D_DIM) + seg * 128 * 8;

    // zero only row 9 (zsrc); rows 10-15 may hold garbage (never consumed)
    for (int i = t; i < 536; i += 256) KTb[9 * 536 + i] = (half_t)0.f;
    {   // stage K rows + K^T + ones row
        int j0 = 2 * t;
        half8v r0 = *(const half8v*)(kg + j0 * 8);
        half8v r1 = *(const half8v*)(kg + j0 * 8 + 8);
        *(half8v*)&Kb[j0 * 8] = r0;
        *(half8v*)&Kb[j0 * 8 + 8] = r1;
        #pragma unroll
        for (int d = 0; d < 8; ++d) {
            KTb[d * 536 + j0] = r0[d];
            KTb[d * 536 + j0 + 1] = r1[d];
        }
        KTb[8 * 536 + j0] = (half_t)1.f;
        KTb[8 * 536 + j0 + 1] = (half_t)1.f;
    }
    if (t < 128) {   // stage Xi = C * q
        half8v hq = *(const half8v*)(qg + t * 8);
        half8v h;
        #pragma unroll
        for (int d = 0; d < 8; ++d) h[d] = (half_t)(C * (float)hq[d]);
        *(half8v*)&Xi[t * 8] = h;
    }
    __syncthreads();

    const half_t* zsrc = &KTb[9 * 536];   // 16B-aligned zeros
    half_t* myP = &Pb[w * 16 * PB_STRIDE];
    float fsum = 0.f;

    for (int it = 0; it < 4; ++it) {
        if (it == 3) {   // swap KTb rows 0-7 to V^T
            __syncthreads();
            int j0 = 2 * t;
            half8v r0 = *(const half8v*)(vg + j0 * 8);
            half8v r1 = *(const half8v*)(vg + j0 * 8 + 8);
            #pragma unroll
            for (int d = 0; d < 8; ++d) {
                KTb[d * 536 + j0] = r0[d];
                KTb[d * 536 + j0 + 1] = r1[d];
            }
            __syncthreads();
        }
        const half_t* x0p = (g2 == 0) ? &Xi[(w * 32 + c16) * 8] : zsrc;
        const half_t* x1p = (g2 == 0) ? &Xi[(w * 32 + 16 + c16) * 8] : zsrc;
        half8v bxi0 = *(const half8v*)x0p;
        half8v bxi1 = *(const half8v*)x1p;
        f32x4 U0 = {0.f, 0.f, 0.f, 0.f}, U1 = {0.f, 0.f, 0.f, 0.f};
        for (int j32 = 0; j32 < 16; ++j32) {
            half8v bKT = *(const half8v*)&KTb[c16 * 536 + j32 * 32 + g2 * 8];
            // ---- i-tile 0 ----
            #pragma unroll
            for (int hh = 0; hh < 2; ++hh) {
                int jt16 = j32 * 2 + hh;
                const half_t* akp = (g2 == 0) ? &Kb[(jt16 * 16 + c16) * 8] : zsrc;
                half8v ak = *(const half8v*)akp;
                f32x4 S = {0.f, 0.f, 0.f, 0.f};
                S = __builtin_amdgcn_mfma_f32_16x16x32_f16(ak, bxi0, S, 0, 0, 0);
                half2v lo = pk2(__builtin_amdgcn_exp2f(S[0]), __builtin_amdgcn_exp2f(S[1]));
                half2v hi = pk2(__builtin_amdgcn_exp2f(S[2]), __builtin_amdgcn_exp2f(S[3]));
                half4v p = __builtin_shufflevector(lo, hi, 0, 1, 2, 3);
                *(half4v*)&myP[c16 * PB_STRIDE + hh * 16 + g2 * 4] = p;
            }
            {
                half4v alo = *(const half4v*)&myP[c16 * PB_STRIDE + g2 * 8];
                half4v ahi = *(const half4v*)&myP[c16 * PB_STRIDE + g2 * 8 + 4];
                half8v ap = __builtin_shufflevector(alo, ahi, 0, 1, 2, 3, 4, 5, 6, 7);
                U0 = __builtin_amdgcn_mfma_f32_16x16x32_f16(ap, bKT, U0, 0, 0, 0);
            }
            // ---- i-tile 1 (reuses myP; same-wave LDS ops are in-order) ----
            #pragma unroll
            for (int hh = 0; hh < 2; ++hh) {
                int jt16 = j32 * 2 + hh;
                const half_t* akp = (g2 == 0) ? &Kb[(jt16 * 16 + c16) * 8] : zsrc;
                half8v ak = *(const half8v*)akp;
                f32x4 S = {0.f, 0.f, 0.f, 0.f};
                S = __builtin_amdgcn_mfma_f32_16x16x32_f16(ak, bxi1, S, 0, 0, 0);
                half2v lo = pk2(__builtin_amdgcn_exp2f(S[0]), __builtin_amdgcn_exp2f(S[1]));
                half2v hi = pk2(__builtin_amdgcn_exp2f(S[2]), __builtin_amdgcn_exp2f(S[3]));
                half4v p = __builtin_shufflevector(lo, hi, 0, 1, 2, 3);
                *(half4v*)&myP[c16 * PB_STRIDE + hh * 16 + g2 * 4] = p;
            }
            {
                half4v alo = *(const half4v*)&myP[c16 * PB_STRIDE + g2 * 8];
                half4v ahi = *(const half4v*)&myP[c16 * PB_STRIDE + g2 * 8 + 4];
                half8v ap = __builtin_shufflevector(alo, ahi, 0, 1, 2, 3, 4, 5, 6, 7);
                U1 = __builtin_amdgcn_mfma_f32_16x16x32_f16(ap, bKT, U1, 0, 0, 0);
            }
        }
        int srcl = (lane & 48) | 8;
        #pragma unroll
        for (int r = 0; r < 4; ++r) {
            float l0 = __shfl(U0[r], srcl, 64);
            float l1 = __shfl(U1[r], srcl, 64);
            float inv0 = __builtin_amdgcn_rcpf(l0);
            float inv1 = __builtin_amdgcn_rcpf(l1);
            if (c16 < 8) {
                int i0 = w * 32 + g2 * 4 + r;
                int i1 = i0 + 16;
                if (it < 3) {
                    Xi[i0 * 8 + c16] = (half_t)(U0[r] * (C * inv0));
                    Xi[i1 * 8 + c16] = (half_t)(U1[r] * (C * inv1));
                } else {
                    fsum += (U0[r] * inv0) * wl2p[i0 * 8 + c16]
                          + (U1[r] * inv1) * wl2p[i1 * 8 + c16];
                }
            }
        }
    }
    float tot = block_reduce_256(fsum);
    if (t == 0) atomicAdd(&y[bh >> 3], tot);
    if (blockIdx.x == 0 && t < 32) {
        atomicAdd(&y[t], c0acc[0]);
    }
}

// ---------------------------------------------------------------------------
extern "C" void kernel_launch(void* const* d_in, const int* in_sizes, int n_in,
                              void* d_out, int out_size, void* d_ws, size_t ws_size,
                              hipStream_t stream) {
    const float* x   = (const float*)d_in[0];
    const float* g_q = (const float*)d_in[1];
    const float* b_q = (const float*)d_in[2];
    const float* g_k = (const float*)d_in[3];
    const float* b_k = (const float*)d_in[4];
    const float* g_v = (const float*)d_in[5];
    const float* b_v = (const float*)d_in[6];
    const float* Wq  = (const float*)d_in[7];
    const float* bq  = (const float*)d_in[8];
    const float* Wk  = (const float*)d_in[9];
    const float* bk  = (const float*)d_in[10];
    const float* Wv  = (const float*)d_in[11];
    const float* bv  = (const float*)d_in[12];
    const float* Wo  = (const float*)d_in[13];
    const float* bo  = (const float*)d_in[14];
    const float* Wl  = (const float*)d_in[15];
    const float* bl  = (const float*)d_in[16];
    float* out = (float*)d_out;

    float* ws = (float*)d_ws;
    float*  colsum = ws;                      // 192
    float*  b2     = ws + 192;                // 192
    float*  c0acc  = ws + 384;                // 1 (+pad to 64)
    float*  Wl2    = ws + 448;                // 32768
    half_t* Wth    = (half_t*)(ws + 33216);   // 98304 halves = 49152 floats
    half_t* qkv16  = (half_t*)(ws + 82368);   // 3*1048576 halves

    half_t* q16 = qkv16;
    half_t* k16 = qkv16 + 1048576;
    half_t* v16 = qkv16 + 2097152;

    prep_w    <<<192, 256, 0, stream>>>(Wq, Wk, Wv, g_q, g_k, g_v,
                                        b_q, b_k, b_v, bq, bk, bv, bl,
                                        Wth, colsum, b2, out, c0acc);
    ln_qkv_wl2<<<1056, 256, 0, stream>>>(x, Wth, b2, colsum, qkv16,
                                         Wl, Wo, bo, Wl2, c0acc);
    hopfield  <<<1024, 256, 0, stream>>>(q16, k16, v16, Wl2, c0acc, out);
}

// Round 12
// 163.945 us; speedup vs baseline: 1.3005x; 1.1614x over previous
//
#include <hip/hip_runtime.h>

#define E_DIM 512
#define N_DIM 512
#define B_DIM 32
#define H_DIM 8
#define D_DIM 8
#define P3    192   // 3 * H * D

typedef _Float16 half_t;
typedef __attribute__((ext_vector_type(2))) _Float16 half2v;
typedef __attribute__((ext_vector_type(4))) _Float16 half4v;
typedef __attribute__((ext_vector_type(8))) _Float16 half8v;
typedef __attribute__((ext_vector_type(4))) float f32x4;

#define PB_STRIDE 36   // hopfield P-scratch stride
#define XS_STRIDE 520  // ln x-tile stride (halves): 260 dw % 32 = 4 -> uniform banks

// ---------------------------------------------------------------------------
__device__ inline float block_reduce_256(float v) {
    __shared__ float red[4];
    #pragma unroll
    for (int m = 32; m >= 1; m >>= 1) v += __shfl_xor(v, m);
    int w = threadIdx.x >> 6;
    if ((threadIdx.x & 63) == 0) red[w] = v;
    __syncthreads();
    if (threadIdx.x == 0) v = red[0] + red[1] + red[2] + red[3];
    return v;
}

__device__ inline half8v cvt8(float4 a, float4 b) {
    half8v h;
    h[0] = (half_t)a.x; h[1] = (half_t)a.y; h[2] = (half_t)a.z; h[3] = (half_t)a.w;
    h[4] = (half_t)b.x; h[5] = (half_t)b.y; h[6] = (half_t)b.z; h[7] = (half_t)b.w;
    return h;
}

__device__ inline half2v pk2(float a, float b) {
    return __builtin_bit_cast(half2v, __builtin_amdgcn_cvt_pkrtz(a, b));
}

// ---------------------------------------------------------------------------
// K0: prep. WthF = f16(W*g) in MFMA-fragment-coalesced layout:
//   WthF[((ct*16 + k32)*64 + g2*16 + c16)*8 + j] = Wth[p'=ct*16+c16][e=k32*32+g2*8+j]
// so ln_qkv's B-fragment load is WthF + (ct*16+k32)*512 + lane*8 (contiguous).
// colsum[p'] = sum of f16-rounded w; b2[p'] = bias + W·ln_beta.
// Block 0 inits y[b]=bl, c0acc=0.
// ---------------------------------------------------------------------------
__global__ __launch_bounds__(256) void prep_w(const float* __restrict__ Wq,
                        const float* __restrict__ Wk, const float* __restrict__ Wv,
                        const float* __restrict__ gq, const float* __restrict__ gk,
                        const float* __restrict__ gv,
                        const float* __restrict__ bnq, const float* __restrict__ bnk,
                        const float* __restrict__ bnv,
                        const float* __restrict__ bq, const float* __restrict__ bk,
                        const float* __restrict__ bv,
                        const float* __restrict__ bl,
                        half_t* __restrict__ WthF, float* __restrict__ colsum,
                        float* __restrict__ b2, float* __restrict__ y,
                        float* __restrict__ c0acc) {
    int pp = blockIdx.x;     // 192
    int which = pp >> 6, p = pp & 63;
    int ct = pp >> 4, c16 = pp & 15;
    const float* W  = (which == 0) ? Wq  : (which == 1) ? Wk  : Wv;
    const float* g  = (which == 0) ? gq  : (which == 1) ? gk  : gv;
    const float* bn = (which == 0) ? bnq : (which == 1) ? bnk : bnv;
    const float* bb = (which == 0) ? bq  : (which == 1) ? bk  : bv;
    int t = threadIdx.x;
    if (pp == 0) {
        if (t < 32) y[t] = bl[0];
        if (t == 32) c0acc[0] = 0.f;
    }
    float cs = 0.f, dt = 0.f;
    #pragma unroll
    for (int l = 0; l < 2; ++l) {
        int e = t + l * 256;
        float wv = W[p * E_DIM + e];
        half_t wh = (half_t)(wv * g[e]);
        int k32 = e >> 5, g2 = (e >> 3) & 3, j = e & 7;
        WthF[(((size_t)(ct * 16 + k32) * 64) + g2 * 16 + c16) * 8 + j] = wh;
        cs += (float)wh;
        dt += wv * bn[e];
    }
    cs = block_reduce_256(cs);
    __syncthreads();
    dt = block_reduce_256(dt);
    if (t == 0) { colsum[pp] = cs; b2[pp] = dt + bb[p]; }
}

// ---------------------------------------------------------------------------
// K1: blocks 0-1023: fused LN+QKV with LDS-staged x (coalesced loads) and
// coalesced WthF B-fragments. One barrier. Blocks 1024-1055: Wl2 via MFMA.
// ---------------------------------------------------------------------------
__global__ __launch_bounds__(256) void ln_qkv_wl2(const float* __restrict__ x,
                                              const half_t* __restrict__ WthF,
                                              const float* __restrict__ b2,
                                              const float* __restrict__ colsum,
                                              half_t* __restrict__ qkv16,
                                              const float* __restrict__ Wl,
                                              const float* __restrict__ Wo,
                                              const float* __restrict__ bo,
                                              float* __restrict__ Wl2,
                                              float* __restrict__ c0acc) {
    __shared__ half_t Xs[16 * XS_STRIDE];   // 16.25 KB
    __shared__ float stats[16][2];
    if (blockIdx.x < 1024) {
        const int t = threadIdx.x;
        const int lane = t & 63;
        const int w = t >> 6;
        const int g2 = lane >> 4, c16 = lane & 15;
        const int row0 = blockIdx.x * 16;
        // ---- stage x -> f16 LDS (coalesced: 16-lane groups read 256B runs) ----
        {
            const int row = t >> 4, c = t & 15;
            const float4* xrow = (const float4*)(x + (size_t)(row0 + row) * E_DIM);
            float sx = 0.f, sxx = 0.f;
            #pragma unroll
            for (int l = 0; l < 8; ++l) {
                int f4 = c + l * 16;
                float4 a = xrow[f4];
                sx  += a.x + a.y + a.z + a.w;
                sxx += a.x*a.x + a.y*a.y + a.z*a.z + a.w*a.w;
                half4v h;
                h[0] = (half_t)a.x; h[1] = (half_t)a.y;
                h[2] = (half_t)a.z; h[3] = (half_t)a.w;
                *(half4v*)&Xs[row * XS_STRIDE + f4 * 4] = h;
            }
            #pragma unroll
            for (int m = 1; m <= 8; m <<= 1) {
                sx += __shfl_xor(sx, m); sxx += __shfl_xor(sxx, m);
            }
            if (c == 0) {
                float mean = sx * (1.f / E_DIM);
                float var  = sxx * (1.f / E_DIM) - mean * mean;
                stats[row][0] = mean;
                stats[row][1] = rsqrtf(var + 1e-5f);
            }
        }
        __syncthreads();
        // ---- K-loop: A from LDS, B from WthF (lane-contiguous) ----
        f32x4 acc[3] = {{0.f,0.f,0.f,0.f},{0.f,0.f,0.f,0.f},{0.f,0.f,0.f,0.f}};
        const half_t* wf = WthF + (size_t)w * 3 * 16 * 512;
        #pragma unroll 4
        for (int k32 = 0; k32 < 16; ++k32) {
            half8v af = *(const half8v*)&Xs[c16 * XS_STRIDE + k32 * 32 + g2 * 8];
            #pragma unroll
            for (int nt = 0; nt < 3; ++nt) {
                half8v bf = *(const half8v*)(wf + ((size_t)(nt * 16 + k32)) * 512 + lane * 8);
                acc[nt] = __builtin_amdgcn_mfma_f32_16x16x32_f16(af, bf, acc[nt], 0, 0, 0);
            }
        }
        // ---- epilogue: LN correction + scattered f16 stores ----
        #pragma unroll
        for (int nt = 0; nt < 3; ++nt) {
            int pp = w * 48 + nt * 16 + c16;
            float cs = colsum[pp], bb = b2[pp];
            int which = pp >> 6, p = pp & 63;
            int h = p >> 3, d = p & 7;
            half_t* dst0 = qkv16 + (size_t)which * (B_DIM * H_DIM * N_DIM * D_DIM);
            #pragma unroll
            for (int r = 0; r < 4; ++r) {
                int rowi = g2 * 4 + r;
                float val = stats[rowi][1] * (acc[nt][r] - stats[rowi][0] * cs) + bb;
                int ng = row0 + rowi;
                int b = ng >> 9, n = ng & 511;
                dst0[(((size_t)(b * H_DIM + h)) * N_DIM + n) * D_DIM + d] = (half_t)val;
            }
        }
    } else {
        // ---- Wl2 MFMA: blk in [0,32) ----
        const int blk = blockIdx.x - 1024;
        const int t = threadIdx.x;
        const int lane = t & 63;
        const int w = t >> 6;
        const int g2 = lane >> 4, c16 = lane & 15;
        const int n0 = blk * 16;
        const int pcol = w * 16;
        f32x4 acc = {0.f, 0.f, 0.f, 0.f};
        float pc = 0.f;
        const float* arow = Wl + (size_t)(n0 + c16) * E_DIM;
        #pragma unroll 2
        for (int k0 = 0; k0 < E_DIM; k0 += 32) {
            int kbase = k0 + g2 * 8;
            float4 a0 = *(const float4*)(arow + kbase);
            float4 a1 = *(const float4*)(arow + kbase + 4);
            if (w == 0) {
                float4 b0 = *(const float4*)(bo + kbase);
                float4 b1 = *(const float4*)(bo + kbase + 4);
                pc += a0.x*b0.x + a0.y*b0.y + a0.z*b0.z + a0.w*b0.w
                    + a1.x*b1.x + a1.y*b1.y + a1.z*b1.z + a1.w*b1.w;
            }
            half8v af = cvt8(a0, a1);
            half8v bf;
            #pragma unroll
            for (int j = 0; j < 8; ++j)
                bf[j] = (half_t)Wo[(size_t)(kbase + j) * 64 + pcol + c16];
            acc = __builtin_amdgcn_mfma_f32_16x16x32_f16(af, bf, acc, 0, 0, 0);
        }
        int p = pcol + c16, h = p >> 3, d = p & 7;
        #pragma unroll
        for (int r = 0; r < 4; ++r) {
            int n = n0 + g2 * 4 + r;
            Wl2[h * (N_DIM * D_DIM) + n * D_DIM + d] = acc[r];
        }
        if (w == 0) {
            pc += __shfl_xor(pc, 16); pc += __shfl_xor(pc, 32);
            pc += __shfl_xor(pc, 1);  pc += __shfl_xor(pc, 2);
            pc += __shfl_xor(pc, 4);  pc += __shfl_xor(pc, 8);
            if (lane == 0) atomicAdd(c0acc, pc);
        }
    }
}

// ---------------------------------------------------------------------------
// K2: MFMA Hopfield + fused classifier — VERBATIM round-11 body (51.2 us,
// VGPR 56, LDS 31.3 KB). Grid 1024 (= 4 blocks/CU; grid-limited).
// ---------------------------------------------------------------------------
__global__ __launch_bounds__(256) void hopfield(const half_t* __restrict__ q16,
                                                const half_t* __restrict__ k16,
                                                const half_t* __restrict__ v16,
                                                const float* __restrict__ Wl2,
                                                const float* __restrict__ c0acc,
                                                float* __restrict__ y) {
    __shared__ half_t Kb[N_DIM * 8];
    __shared__ half_t Xi[128 * 8];
    __shared__ half_t KTb[16 * 536];
    __shared__ half_t Pb[4 * 16 * PB_STRIDE];
    const int t = threadIdx.x;
    const int lane = t & 63;
    const int w = t >> 6;
    const int g2 = lane >> 4;
    const int c16 = lane & 15;
    const int bh = blockIdx.x >> 2, seg = blockIdx.x & 3;
    const float C = 0.25f * 1.44269504088896f;
    const half_t* kg = k16 + (size_t)bh * (N_DIM * D_DIM);
    const half_t* vg = v16 + (size_t)bh * (N_DIM * D_DIM);
    const half_t* qg = q16 + (size_t)bh * (N_DIM * D_DIM) + seg * 128 * 8;
    const float* wl2p = Wl2 + (bh & 7) * (N_DIM * D_DIM) + seg * 128 * 8;

    for (int i = t; i < 536; i += 256) KTb[9 * 536 + i] = (half_t)0.f;
    {   // stage K rows + K^T + ones row
        int j0 = 2 * t;
        half8v r0 = *(const half8v*)(kg + j0 * 8);
        half8v r1 = *(const half8v*)(kg + j0 * 8 + 8);
        *(half8v*)&Kb[j0 * 8] = r0;
        *(half8v*)&Kb[j0 * 8 + 8] = r1;
        #pragma unroll
        for (int d = 0; d < 8; ++d) {
            KTb[d * 536 + j0] = r0[d];
            KTb[d * 536 + j0 + 1] = r1[d];
        }
        KTb[8 * 536 + j0] = (half_t)1.f;
        KTb[8 * 536 + j0 + 1] = (half_t)1.f;
    }
    if (t < 128) {   // stage Xi = C * q
        half8v hq = *(const half8v*)(qg + t * 8);
        half8v h;
        #pragma unroll
        for (int d = 0; d < 8; ++d) h[d] = (half_t)(C * (float)hq[d]);
        *(half8v*)&Xi[t * 8] = h;
    }
    __syncthreads();

    const half_t* zsrc = &KTb[9 * 536];
    half_t* myP = &Pb[w * 16 * PB_STRIDE];
    float fsum = 0.f;

    for (int it = 0; it < 4; ++it) {
        if (it == 3) {   // swap KTb rows 0-7 to V^T
            __syncthreads();
            int j0 = 2 * t;
            half8v r0 = *(const half8v*)(vg + j0 * 8);
            half8v r1 = *(const half8v*)(vg + j0 * 8 + 8);
            #pragma unroll
            for (int d = 0; d < 8; ++d) {
                KTb[d * 536 + j0] = r0[d];
                KTb[d * 536 + j0 + 1] = r1[d];
            }
            __syncthreads();
        }
        const half_t* x0p = (g2 == 0) ? &Xi[(w * 32 + c16) * 8] : zsrc;
        const half_t* x1p = (g2 == 0) ? &Xi[(w * 32 + 16 + c16) * 8] : zsrc;
        half8v bxi0 = *(const half8v*)x0p;
        half8v bxi1 = *(const half8v*)x1p;
        f32x4 U0 = {0.f, 0.f, 0.f, 0.f}, U1 = {0.f, 0.f, 0.f, 0.f};
        for (int j32 = 0; j32 < 16; ++j32) {
            half8v bKT = *(const half8v*)&KTb[c16 * 536 + j32 * 32 + g2 * 8];
            #pragma unroll
            for (int hh = 0; hh < 2; ++hh) {
                int jt16 = j32 * 2 + hh;
                const half_t* akp = (g2 == 0) ? &Kb[(jt16 * 16 + c16) * 8] : zsrc;
                half8v ak = *(const half8v*)akp;
                f32x4 S = {0.f, 0.f, 0.f, 0.f};
                S = __builtin_amdgcn_mfma_f32_16x16x32_f16(ak, bxi0, S, 0, 0, 0);
                half2v lo = pk2(__builtin_amdgcn_exp2f(S[0]), __builtin_amdgcn_exp2f(S[1]));
                half2v hi = pk2(__builtin_amdgcn_exp2f(S[2]), __builtin_amdgcn_exp2f(S[3]));
                half4v p = __builtin_shufflevector(lo, hi, 0, 1, 2, 3);
                *(half4v*)&myP[c16 * PB_STRIDE + hh * 16 + g2 * 4] = p;
            }
            {
                half4v alo = *(const half4v*)&myP[c16 * PB_STRIDE + g2 * 8];
                half4v ahi = *(const half4v*)&myP[c16 * PB_STRIDE + g2 * 8 + 4];
                half8v ap = __builtin_shufflevector(alo, ahi, 0, 1, 2, 3, 4, 5, 6, 7);
                U0 = __builtin_amdgcn_mfma_f32_16x16x32_f16(ap, bKT, U0, 0, 0, 0);
            }
            #pragma unroll
            for (int hh = 0; hh < 2; ++hh) {
                int jt16 = j32 * 2 + hh;
                const half_t* akp = (g2 == 0) ? &Kb[(jt16 * 16 + c16) * 8] : zsrc;
                half8v ak = *(const half8v*)akp;
                f32x4 S = {0.f, 0.f, 0.f, 0.f};
                S = __builtin_amdgcn_mfma_f32_16x16x32_f16(ak, bxi1, S, 0, 0, 0);
                half2v lo = pk2(__builtin_amdgcn_exp2f(S[0]), __builtin_amdgcn_exp2f(S[1]));
                half2v hi = pk2(__builtin_amdgcn_exp2f(S[2]), __builtin_amdgcn_exp2f(S[3]));
                half4v p = __builtin_shufflevector(lo, hi, 0, 1, 2, 3);
                *(half4v*)&myP[c16 * PB_STRIDE + hh * 16 + g2 * 4] = p;
            }
            {
                half4v alo = *(const half4v*)&myP[c16 * PB_STRIDE + g2 * 8];
                half4v ahi = *(const half4v*)&myP[c16 * PB_STRIDE + g2 * 8 + 4];
                half8v ap = __builtin_shufflevector(alo, ahi, 0, 1, 2, 3, 4, 5, 6, 7);
                U1 = __builtin_amdgcn_mfma_f32_16x16x32_f16(ap, bKT, U1, 0, 0, 0);
            }
        }
        int srcl = (lane & 48) | 8;
        #pragma unroll
        for (int r = 0; r < 4; ++r) {
            float l0 = __shfl(U0[r], srcl, 64);
            float l1 = __shfl(U1[r], srcl, 64);
            float inv0 = __builtin_amdgcn_rcpf(l0);
            float inv1 = __builtin_amdgcn_rcpf(l1);
            if (c16 < 8) {
                int i0 = w * 32 + g2 * 4 + r;
                int i1 = i0 + 16;
                if (it < 3) {
                    Xi[i0 * 8 + c16] = (half_t)(U0[r] * (C * inv0));
                    Xi[i1 * 8 + c16] = (half_t)(U1[r] * (C * inv1));
                } else {
                    fsum += (U0[r] * inv0) * wl2p[i0 * 8 + c16]
                          + (U1[r] * inv1) * wl2p[i1 * 8 + c16];
                }
            }
        }
    }
    float tot = block_reduce_256(fsum);
    if (t == 0) atomicAdd(&y[bh >> 3], tot);
    if (blockIdx.x == 0 && t < 32) {
        atomicAdd(&y[t], c0acc[0]);
    }
}

// ---------------------------------------------------------------------------
extern "C" void kernel_launch(void* const* d_in, const int* in_sizes, int n_in,
                              void* d_out, int out_size, void* d_ws, size_t ws_size,
                              hipStream_t stream) {
    const float* x   = (const float*)d_in[0];
    const float* g_q = (const float*)d_in[1];
    const float* b_q = (const float*)d_in[2];
    const float* g_k = (const float*)d_in[3];
    const float* b_k = (const float*)d_in[4];
    const float* g_v = (const float*)d_in[5];
    const float* b_v = (const float*)d_in[6];
    const float* Wq  = (const float*)d_in[7];
    const float* bq  = (const float*)d_in[8];
    const float* Wk  = (const float*)d_in[9];
    const float* bk  = (const float*)d_in[10];
    const float* Wv  = (const float*)d_in[11];
    const float* bv  = (const float*)d_in[12];
    const float* Wo  = (const float*)d_in[13];
    const float* bo  = (const float*)d_in[14];
    const float* Wl  = (const float*)d_in[15];
    const float* bl  = (const float*)d_in[16];
    float* out = (float*)d_out;

    float* ws = (float*)d_ws;
    float*  colsum = ws;                      // 192
    float*  b2     = ws + 192;                // 192
    float*  c0acc  = ws + 384;                // 1 (+pad to 64)
    float*  Wl2    = ws + 448;                // 32768
    half_t* WthF   = (half_t*)(ws + 33216);   // 98304 halves = 49152 floats
    half_t* qkv16  = (half_t*)(ws + 82368);   // 3*1048576 halves

    half_t* q16 = qkv16;
    half_t* k16 = qkv16 + 1048576;
    half_t* v16 = qkv16 + 2097152;

    prep_w    <<<192, 256, 0, stream>>>(Wq, Wk, Wv, g_q, g_k, g_v,
                                        b_q, b_k, b_v, bq, bk, bv, bl,
                                        WthF, colsum, b2, out, c0acc);
    ln_qkv_wl2<<<1056, 256, 0, stream>>>(x, WthF, b2, colsum, qkv16,
                                         Wl, Wo, bo, Wl2, c0acc);
    hopfield  <<<1024, 256, 0, stream>>>(q16, k16, v16, Wl2, c0acc, out);
}